// Round 7
// baseline (273.720 us; speedup 1.0000x reference)
//
#include <hip/hip_runtime.h>

#define N_NODES 100000
#define N_EDGESV 1000000
#define N_REL 7
#define IN_CH 128
#define HID_CH 64
#define NBINS 800000          // (dst, rel) bins: key = d*8 + r
#define OFFM 0x0FFFFFFFu
#define NTILES 6250           // N_NODES / 16
#define NSB 196               // super-buckets: dst>>9 (512 nodes each)
#define SBCAP 8192            // mean 5102, sigma~71 -> +43 sigma margin
#define NBLK_A1 512
#define CHUNK 1954            // ceil(1e6 / 512)
#define XH_BLOCKS 2048
#define WB_BLOCKS 64
#define XH_TOTAL (N_NODES * IN_CH / 4)

typedef _Float16 f16;
typedef __attribute__((ext_vector_type(8))) _Float16 f16x8;
typedef __attribute__((ext_vector_type(4))) _Float16 f16x4;
typedef __attribute__((ext_vector_type(4))) float f32x4;

// ================= K1: fused passA1 | xh | wbuild (independent roles, 256 thr) =================
// wbuild writes wbt with the t<->quad row PERMUTATION (round-1/4 verified): physical row p
// holds logical col (p&~63)|perm(p&63), perm(l) = ((l&15)>>2)*16 + ((l>>4)<<2) + (l&3).
__global__ __launch_bounds__(256)
void k1_fused_kernel(const int* __restrict__ ei, const int* __restrict__ et,
                     int* __restrict__ gcur, int2* __restrict__ btmp,
                     const float* __restrict__ x, f16* __restrict__ xh,
                     const float* __restrict__ root1, const float* __restrict__ W1,
                     const float* __restrict__ comp2, const float* __restrict__ basis2,
                     const float* __restrict__ root2, f16* __restrict__ wbt,
                     f16* __restrict__ w2t)
{
    __shared__ int2 ent[CHUNK];          // 15632 B (passA1 role only)
    __shared__ int lhist[NSB], lcur[NSB], gposl[NSB];
    const int bid = blockIdx.x;

    if (bid < NBLK_A1) {
        // ---- role: passA1 (LDS-binned radix scatter by dst>>9) ----
        const int cbase = bid * CHUNK;
        const int cnt = min(CHUNK, N_EDGESV - cbase);

        for (int i = threadIdx.x; i < NSB; i += 256) { lhist[i] = 0; lcur[i] = 0; }
        __syncthreads();

        for (int i = threadIdx.x; i < cnt; i += 256) {
            int e = cbase + i;
            int d = ei[N_EDGESV + e];
            int s = ei[e];
            int r = et[e];
            ent[i] = make_int2((d << 3) + r, (s * 1024 + 128 + r * 128) | (r << 28));
            atomicAdd(&lhist[d >> 9], 1);
        }
        __syncthreads();

        for (int b = threadIdx.x; b < NSB; b += 256)
            gposl[b] = atomicAdd(&gcur[b], lhist[b]);
        __syncthreads();

        for (int i = threadIdx.x; i < cnt; i += 256) {
            int2 en = ent[i];
            int b = en.x >> 12;
            int off = atomicAdd(&lcur[b], 1);
            int idx = gposl[b] + off;
            if (idx < SBCAP) btmp[(size_t)b * SBCAP + idx] = en;
        }
    } else if (bid < NBLK_A1 + XH_BLOCKS) {
        // ---- role: xh (x fp32 -> fp16) ----
        for (int i = (bid - NBLK_A1) * 256 + threadIdx.x; i < XH_TOTAL;
             i += XH_BLOCKS * 256) {
            float4 v = ((const float4*)x)[i];
            f16x4 o = {(f16)v.x, (f16)v.y, (f16)v.z, (f16)v.w};
            *(f16x4*)(xh + (size_t)i * 4) = o;
        }
    } else {
        // ---- role: wbuild (Wb_t[512][128] permuted + W2_t[16][64]) ----
        const int t0 = (bid - NBLK_A1 - XH_BLOCKS) * 256 + threadIdx.x;
        for (int idx = t0; idx < 512 * 128; idx += WB_BLOCKS * 256) {
            int p = idx >> 7, k = idx & 127;
            int lp = p & 63;
            int lc = ((lp & 15) >> 2) * 16 + ((lp >> 4) << 2) + (lp & 3);
            int col = (p & ~63) | lc;               // logical output column
            float v;
            if (col < 64) {
                v = root1[k * HID_CH + col];
            } else {
                int cc = col - 64, r = cc >> 6, inner = cc & 63, b = inner >> 4, j = inner & 15;
                int kb = k - b * 32;
                v = (kb >= 0 && kb < 32) ? W1[(((r * 4 + b) * 32) + kb) * 16 + j] : 0.f;
            }
            wbt[idx] = (f16)v;
        }
        for (int idx = t0; idx < 16 * 64; idx += WB_BLOCKS * 256) {
            int col = idx >> 6, k = idx & 63;
            float v;
            if (col < 14) {
                int r = col >> 1, oc = col & 1;
                v = 0.f;
                for (int b = 0; b < 4; ++b) v += comp2[r * 4 + b] * basis2[(b * 64 + k) * 2 + oc];
            } else {
                v = root2[k * 2 + (col - 14)];
            }
            w2t[idx] = (f16)v;
        }
    }
}

// ========== gemm1 (MFMA, LDS-free, barrier-free; round-4 proven 49us) ==========
__global__ __launch_bounds__(512, 4)
void gemm1_kernel(const f16* __restrict__ xh, const f16* __restrict__ wbt,
                  f16* __restrict__ dense1) {
    const int lane = threadIdx.x & 63;
    const int wv = threadIdx.x >> 6;
    const int m = lane & 15;
    const int quad = lane >> 4;

    f16x8 bf[4][4];
#pragma unroll
    for (int t = 0; t < 4; ++t) {
        const f16* wc = wbt + (size_t)(wv * 64 + t * 16 + m) * 128 + quad * 8;
#pragma unroll
        for (int kk = 0; kk < 4; ++kk)
            bf[t][kk] = *(const f16x8*)(wc + kk * 32);
    }

    int tile = blockIdx.x;
    f16x8 a[4];
    if (tile < NTILES) {
        const f16* xrow = xh + (size_t)(tile * 16 + m) * 128 + quad * 8;
#pragma unroll
        for (int kk = 0; kk < 4; ++kk) a[kk] = *(const f16x8*)(xrow + kk * 32);
    }

    while (tile < NTILES) {
        const int n0 = tile * 16;
        const int next = tile + gridDim.x;

        f16x8 hv[2];
#pragma unroll
        for (int t = 0; t < 4; ++t) {
            f32x4 acc = {0.f, 0.f, 0.f, 0.f};
#pragma unroll
            for (int kk = 0; kk < 4; ++kk)
                acc = __builtin_amdgcn_mfma_f32_16x16x32_f16(bf[t][kk], a[kk], acc, 0, 0, 0);
#pragma unroll
            for (int i = 0; i < 4; ++i)
                hv[t >> 1][(t & 1) * 4 + i] = (f16)acc[i];
        }

        if (next < NTILES) {  // prefetch next A (WAR on a[]: safe after MFMA issue)
            const f16* xrow = xh + (size_t)(next * 16 + m) * 128 + quad * 8;
#pragma unroll
            for (int kk = 0; kk < 4; ++kk) a[kk] = *(const f16x8*)(xrow + kk * 32);
        }

        f16* dst = dense1 + (size_t)(n0 + m) * 512 + wv * 64 + quad * 16;
        *(f16x8*)dst       = hv[0];
        *(f16x8*)(dst + 8) = hv[1];
        tile = next;
    }
}

// ========== passA2: 256 thr, bucketscan INLINED (round-3 proven) ==========
__global__ __launch_bounds__(256)
void passA2_kernel(const int* __restrict__ gcur, const int2* __restrict__ btmp,
                   int* __restrict__ off2, int* __restrict__ packed1) {
    __shared__ int hist[4096];  // 16 KB: bucket-local bins (d&511)*8+r
    __shared__ int aux[256];
    __shared__ int shv[1];
    const int b = blockIdx.x >> 2;
    const int q = blockIdx.x & 3;
    const int t = threadIdx.x;

    if (blockIdx.x == 0 && t == 0) off2[0] = 0;

    // phase 0: inline bucket-base scan over gcur[0..NSB)
    int v0 = (t < NSB) ? min(gcur[t], SBCAP) : 0;
    aux[t] = v0;
    __syncthreads();
    for (int d = 1; d < 256; d <<= 1) {
        int xv = (t >= d) ? aux[t - d] : 0;
        __syncthreads();
        if (t >= d) aux[t] += xv;
        __syncthreads();
    }
    if (t == 0) shv[0] = (b == 0) ? 0 : aux[b - 1];   // exclusive base
    __syncthreads();
    const int gb = shv[0];
    const int cnt = min(gcur[b], SBCAP);
    const int2* base = btmp + (size_t)b * SBCAP;
    __syncthreads();                                  // aux reused below

    // phase 1: bucket-local histogram
    for (int i = t; i < 4096; i += 256) hist[i] = 0;
    __syncthreads();
    for (int i = t; i < cnt; i += 256) atomicAdd(&hist[base[i].x & 4095], 1);
    __syncthreads();

    // phase 2: block-wide exclusive scan over 4096 bins (16 bins/thread)
    int loc[16];
    int run = 0;
#pragma unroll
    for (int j = 0; j < 16; ++j) { loc[j] = run; run += hist[t * 16 + j]; }
    aux[t] = run;
    __syncthreads();
    for (int d = 1; d < 256; d <<= 1) {
        int xv = (t >= d) ? aux[t - d] : 0;
        __syncthreads();
        if (t >= d) aux[t] += xv;
        __syncthreads();
    }
    const int tbase = aux[t] - run;
    __syncthreads();

#pragma unroll
    for (int j = 0; j < 16; ++j) {
        int bin = t * 16 + j;
        int excl = tbase + loc[j];
        int incl = excl + hist[bin];            // read before overwrite (same bin)
        if ((t >> 6) == q) {                    // my quarter's bins only
            int gkey = (b << 12) + bin;
            if (gkey < NBINS) off2[gkey + 1] = gb + incl;
        }
        hist[bin] = excl;                       // becomes bucket-relative cursor
    }
    __syncthreads();

    for (int i = t; i < cnt; i += 256) {        // place my quarter's edges
        int2 e = base[i];
        int lb = e.x & 4095;
        if ((lb >> 10) == q) {
            int pos = gb + atomicAdd(&hist[lb], 1);
            packed1[pos] = e.y;
        }
    }
}

// ========== agg1+pre2 fused, TWO NODES PER WAVE ==========
// agg1 is wave-level latency-bound (VALU 43%, HBM 22%, occ 67% -> no pipe saturated).
// Each wave now interleaves two independent merge chains (nodes 2P, 2P+1): the dual
// main loop issues 4+4 gather loads from independent chains per iteration, doubling
// MLP and VALU-chain ILP per wave. Tails use the proven single-node path (bit-identical
// per-node merge semantics). Gather base pre-biased by lane*2.
__global__ __launch_bounds__(256)
void agg1_kernel(const f16* __restrict__ dense1, const float* __restrict__ bias1,
                 const float* __restrict__ bias2, const f16* __restrict__ w2t,
                 const int* __restrict__ off2, const int* __restrict__ packed1,
                 float* __restrict__ msg2)
{
    __shared__ float hbuf[4][64];
    const int lane = threadIdx.x & 63;
    const int wv = threadIdx.x >> 6;
    const char* m1l = (const char*)dense1 + lane * 2;   // pre-biased gather base
    const int wid = blockIdx.x * 4 + wv;
    const int nw = gridDim.x * 4;
    const float bias = bias1[lane];

    // per-lane W2 slice: lane (kq, c) holds w2t[c][kq*16 .. +16) as f32
    const int c = lane & 15;
    const int kq = lane >> 4;
    float w2v[16];
#pragma unroll
    for (int j = 0; j < 16; ++j) w2v[j] = (float)w2t[c * 64 + kq * 16 + j];
    const float badd = (c == 14) ? bias2[0] : ((c == 15) ? bias2[1] : 0.f);

#define MRGS(prev, add, cur, kk, vv) { \
    int r_ = (int)((kk) >> 28); \
    bool same_ = (r_ == (prev)); \
    (add) += same_ ? 0.f : (cur); \
    (cur) = same_ ? fmaxf((cur), (vv)) : (vv); \
    (prev) = r_; }

    for (int P = wid; P < N_NODES / 2; P += nw) {
        const int nA = P * 2;
        const int nB = nA + 1;
        const int stA = off2[nA << 3];
        const int enA = off2[(nA << 3) + 7];
        const int stB = off2[nB << 3];
        const int enB = off2[(nB << 3) + 7];
        const float hrootA = (float)dense1[(size_t)nA * 512 + lane];  // issue early
        const float hrootB = (float)dense1[(size_t)nB * 512 + lane];

        float addA = 0.f, curA = 0.f, addB = 0.f, curB = 0.f;
        int prevA = -1, prevB = -1;
        int pA = stA, pB = stB;

        // dual main loop: 4 edges of A + 4 of B, independent chains
        while (pA + 3 < enA && pB + 3 < enB) {
            unsigned a0 = (unsigned)packed1[pA];
            unsigned a1 = (unsigned)packed1[pA + 1];
            unsigned a2 = (unsigned)packed1[pA + 2];
            unsigned a3 = (unsigned)packed1[pA + 3];
            unsigned b0 = (unsigned)packed1[pB];
            unsigned b1 = (unsigned)packed1[pB + 1];
            unsigned b2 = (unsigned)packed1[pB + 2];
            unsigned b3 = (unsigned)packed1[pB + 3];
            float va0 = (float)*(const f16*)(m1l + (a0 & OFFM));
            float va1 = (float)*(const f16*)(m1l + (a1 & OFFM));
            float va2 = (float)*(const f16*)(m1l + (a2 & OFFM));
            float va3 = (float)*(const f16*)(m1l + (a3 & OFFM));
            float vb0 = (float)*(const f16*)(m1l + (b0 & OFFM));
            float vb1 = (float)*(const f16*)(m1l + (b1 & OFFM));
            float vb2 = (float)*(const f16*)(m1l + (b2 & OFFM));
            float vb3 = (float)*(const f16*)(m1l + (b3 & OFFM));
            MRGS(prevA, addA, curA, a0, va0) MRGS(prevB, addB, curB, b0, vb0)
            MRGS(prevA, addA, curA, a1, va1) MRGS(prevB, addB, curB, b1, vb1)
            MRGS(prevA, addA, curA, a2, va2) MRGS(prevB, addB, curB, b2, vb2)
            MRGS(prevA, addA, curA, a3, va3) MRGS(prevB, addB, curB, b3, vb3)
            pA += 4; pB += 4;
        }
        // tail A (proven single-node path)
        for (; pA + 3 < enA; pA += 4) {
            unsigned k0 = (unsigned)packed1[pA];
            unsigned k1 = (unsigned)packed1[pA + 1];
            unsigned k2 = (unsigned)packed1[pA + 2];
            unsigned k3 = (unsigned)packed1[pA + 3];
            float v0 = (float)*(const f16*)(m1l + (k0 & OFFM));
            float v1 = (float)*(const f16*)(m1l + (k1 & OFFM));
            float v2 = (float)*(const f16*)(m1l + (k2 & OFFM));
            float v3 = (float)*(const f16*)(m1l + (k3 & OFFM));
            MRGS(prevA, addA, curA, k0, v0) MRGS(prevA, addA, curA, k1, v1)
            MRGS(prevA, addA, curA, k2, v2) MRGS(prevA, addA, curA, k3, v3)
        }
        for (; pA < enA; ++pA) {
            unsigned k0 = (unsigned)packed1[pA];
            float v0 = (float)*(const f16*)(m1l + (k0 & OFFM));
            MRGS(prevA, addA, curA, k0, v0)
        }
        // tail B
        for (; pB + 3 < enB; pB += 4) {
            unsigned k0 = (unsigned)packed1[pB];
            unsigned k1 = (unsigned)packed1[pB + 1];
            unsigned k2 = (unsigned)packed1[pB + 2];
            unsigned k3 = (unsigned)packed1[pB + 3];
            float v0 = (float)*(const f16*)(m1l + (k0 & OFFM));
            float v1 = (float)*(const f16*)(m1l + (k1 & OFFM));
            float v2 = (float)*(const f16*)(m1l + (k2 & OFFM));
            float v3 = (float)*(const f16*)(m1l + (k3 & OFFM));
            MRGS(prevB, addB, curB, k0, v0) MRGS(prevB, addB, curB, k1, v1)
            MRGS(prevB, addB, curB, k2, v2) MRGS(prevB, addB, curB, k3, v3)
        }
        for (; pB < enB; ++pB) {
            unsigned k0 = (unsigned)packed1[pB];
            float v0 = (float)*(const f16*)(m1l + (k0 & OFFM));
            MRGS(prevB, addB, curB, k0, v0)
        }
        addA += curA;
        addB += curB;

        const float hvalA = fmaxf(hrootA + bias + addA, 0.f);
        const float hvalB = fmaxf(hrootB + bias + addB, 0.f);

        // ---- fused pre2 for node A ----
        hbuf[wv][lane] = hvalA;              // intra-wave LDS broadcast (in-order DS)
        float partA = 0.f;
#pragma unroll
        for (int j = 0; j < 16; ++j) partA += hbuf[wv][kq * 16 + j] * w2v[j];
        partA += __shfl_xor(partA, 16);
        partA += __shfl_xor(partA, 32);
        // ---- fused pre2 for node B ----
        hbuf[wv][lane] = hvalB;
        float partB = 0.f;
#pragma unroll
        for (int j = 0; j < 16; ++j) partB += hbuf[wv][kq * 16 + j] * w2v[j];
        partB += __shfl_xor(partB, 16);
        partB += __shfl_xor(partB, 32);
        if (lane < 16) {
            msg2[(size_t)nA * 16 + c] = partA + badd;
            msg2[(size_t)nB * 16 + c] = partB + badd;
        }
    }
#undef MRGS
}

// ========== agg2: thread/node; merged edge loop, unroll 8 (unchanged) ==========
__global__ __launch_bounds__(256)
void agg2_kernel(const float* __restrict__ msg2, const int* __restrict__ off2,
                 const int* __restrict__ packed1, float* __restrict__ out)
{
    const int n = blockIdx.x * blockDim.x + threadIdx.x;
    if (n >= N_NODES) return;
    const char* m2 = (const char*)msg2;
    const int st = off2[n << 3];
    const int en = off2[(n << 3) + 7];
    float addx = 0.f, addy = 0.f, curx = 0.f, cury = 0.f;
    int prev_r = -1;

#define MRG2(kk, ff) { \
    int r_ = (int)((kk) >> 28); \
    bool same_ = (r_ == prev_r); \
    addx += same_ ? 0.f : curx; \
    addy += same_ ? 0.f : cury; \
    curx = same_ ? fmaxf(curx, (ff).x) : (ff).x; \
    cury = same_ ? fmaxf(cury, (ff).y) : (ff).y; \
    prev_r = r_; }

    int p = st;
    for (; p + 7 < en; p += 8) {
        unsigned k0 = (unsigned)packed1[p],     k1 = (unsigned)packed1[p + 1];
        unsigned k2 = (unsigned)packed1[p + 2], k3 = (unsigned)packed1[p + 3];
        unsigned k4 = (unsigned)packed1[p + 4], k5 = (unsigned)packed1[p + 5];
        unsigned k6 = (unsigned)packed1[p + 6], k7 = (unsigned)packed1[p + 7];
        float2 f0 = *(const float2*)(m2 + (((k0 & OFFM) >> 4) - 8));
        float2 f1 = *(const float2*)(m2 + (((k1 & OFFM) >> 4) - 8));
        float2 f2 = *(const float2*)(m2 + (((k2 & OFFM) >> 4) - 8));
        float2 f3 = *(const float2*)(m2 + (((k3 & OFFM) >> 4) - 8));
        float2 f4 = *(const float2*)(m2 + (((k4 & OFFM) >> 4) - 8));
        float2 f5 = *(const float2*)(m2 + (((k5 & OFFM) >> 4) - 8));
        float2 f6 = *(const float2*)(m2 + (((k6 & OFFM) >> 4) - 8));
        float2 f7 = *(const float2*)(m2 + (((k7 & OFFM) >> 4) - 8));
        MRG2(k0, f0) MRG2(k1, f1) MRG2(k2, f2) MRG2(k3, f3)
        MRG2(k4, f4) MRG2(k5, f5) MRG2(k6, f6) MRG2(k7, f7)
    }
    for (; p < en; ++p) {
        unsigned k0 = (unsigned)packed1[p];
        float2 f0 = *(const float2*)(m2 + (((k0 & OFFM) >> 4) - 8));
        MRG2(k0, f0)
    }
#undef MRG2

    out[(size_t)n * 2 + 0] = msg2[(size_t)n * 16 + 14] + addx + curx;
    out[(size_t)n * 2 + 1] = msg2[(size_t)n * 16 + 15] + addy + cury;
}

extern "C" void kernel_launch(void* const* d_in, const int* in_sizes, int n_in,
                              void* d_out, int out_size, void* d_ws, size_t ws_size,
                              hipStream_t stream)
{
    const float* x      = (const float*)d_in[0];
    const int*   ei     = (const int*)d_in[1];
    const int*   et     = (const int*)d_in[2];
    const float* W1     = (const float*)d_in[3];
    const float* root1  = (const float*)d_in[4];
    const float* bias1  = (const float*)d_in[5];
    const float* comp2  = (const float*)d_in[6];
    const float* basis2 = (const float*)d_in[7];
    const float* root2  = (const float*)d_in[8];
    const float* bias2  = (const float*)d_in[9];
    float* out = (float*)d_out;

    // workspace carve-up
    char* ws = (char*)d_ws;
    size_t o = 0;
    auto carve = [&](size_t bytes) { char* p = ws + o; o += (bytes + 255) & ~(size_t)255; return p; };
    int*   off2    = (int*)carve(sizeof(int) * (NBINS + 1));
    int*   gcur    = (int*)carve(sizeof(int) * NSB);
    int2*  btmp    = (int2*)carve(sizeof(int2) * (size_t)NSB * SBCAP);           // 12.8 MB
    int*   packed1 = (int*)carve(sizeof(int) * N_EDGESV);
    f16*   xh      = (f16*)carve(sizeof(f16) * (size_t)N_NODES * IN_CH);         // 25.6 MB
    f16*   wbt     = (f16*)carve(sizeof(f16) * 512 * 128);
    f16*   w2t     = (f16*)carve(sizeof(f16) * 16 * 64);
    f16*   dense1  = (f16*)carve(sizeof(f16) * (size_t)N_NODES * 512);           // 102.4 MB
    float* msg2    = (float*)carve(sizeof(float) * (size_t)N_NODES * 16);        //  6.4 MB

    hipMemsetAsync(gcur, 0, sizeof(int) * NSB, stream);

    // K1: passA1 | xh | wbuild (independent roles)
    k1_fused_kernel<<<NBLK_A1 + XH_BLOCKS + WB_BLOCKS, 256, 0, stream>>>(
        ei, et, gcur, btmp, x, xh, root1, W1, comp2, basis2, root2, wbt, w2t);

    // dense precompute (round-4 proven LDS-free swapped-operand MFMA)
    gemm1_kernel<<<1024, 512, 0, stream>>>(xh, wbt, dense1);

    // CSR finalize (bucketscan inlined)
    passA2_kernel<<<NSB * 4, 256, 0, stream>>>(gcur, btmp, off2, packed1);

    // layer-1 aggregation (2 nodes/wave) + fused layer-2 message precompute
    agg1_kernel<<<2048, 256, 0, stream>>>(dense1, bias1, bias2, w2t, off2, packed1, msg2);

    // layer-2 aggregation
    agg2_kernel<<<(N_NODES + 255) / 256, 256, 0, stream>>>(msg2, off2, packed1, out);
}

// Round 8
// 257.135 us; speedup vs baseline: 1.0645x; 1.0645x over previous
//
#include <hip/hip_runtime.h>

#define N_NODES 100000
#define N_EDGESV 1000000
#define N_REL 7
#define IN_CH 128
#define HID_CH 64
#define NBINS 800000          // (dst, rel) bins: key = d*8 + r
#define OFFM 0x0FFFFFFFu
#define NTILES 6250           // N_NODES / 16
#define NSB 196               // super-buckets: dst>>9 (512 nodes each)
#define SBCAP 8192            // mean 5102, sigma~71 -> +43 sigma margin
#define NBLK_A1 512
#define CHUNK 1954            // ceil(1e6 / 512)
#define XH_BLOCKS 2048
#define WB_BLOCKS 64
#define XH_TOTAL (N_NODES * IN_CH / 4)

typedef _Float16 f16;
typedef __attribute__((ext_vector_type(8))) _Float16 f16x8;
typedef __attribute__((ext_vector_type(4))) _Float16 f16x4;
typedef __attribute__((ext_vector_type(4))) float f32x4;

// ================= K1: fused passA1 | xh | wbuild (independent roles, 256 thr) =================
// wbuild writes wbt with the t<->quad row PERMUTATION (round-1/4 verified): physical row p
// holds logical col (p&~63)|perm(p&63), perm(l) = ((l&15)>>2)*16 + ((l>>4)<<2) + (l&3).
__global__ __launch_bounds__(256)
void k1_fused_kernel(const int* __restrict__ ei, const int* __restrict__ et,
                     int* __restrict__ gcur, int2* __restrict__ btmp,
                     const float* __restrict__ x, f16* __restrict__ xh,
                     const float* __restrict__ root1, const float* __restrict__ W1,
                     const float* __restrict__ comp2, const float* __restrict__ basis2,
                     const float* __restrict__ root2, f16* __restrict__ wbt,
                     f16* __restrict__ w2t)
{
    __shared__ int2 ent[CHUNK];          // 15632 B (passA1 role only)
    __shared__ int lhist[NSB], lcur[NSB], gposl[NSB];
    const int bid = blockIdx.x;

    if (bid < NBLK_A1) {
        // ---- role: passA1 (LDS-binned radix scatter by dst>>9) ----
        const int cbase = bid * CHUNK;
        const int cnt = min(CHUNK, N_EDGESV - cbase);

        for (int i = threadIdx.x; i < NSB; i += 256) { lhist[i] = 0; lcur[i] = 0; }
        __syncthreads();

        for (int i = threadIdx.x; i < cnt; i += 256) {
            int e = cbase + i;
            int d = ei[N_EDGESV + e];
            int s = ei[e];
            int r = et[e];
            ent[i] = make_int2((d << 3) + r, (s * 1024 + 128 + r * 128) | (r << 28));
            atomicAdd(&lhist[d >> 9], 1);
        }
        __syncthreads();

        for (int b = threadIdx.x; b < NSB; b += 256)
            gposl[b] = atomicAdd(&gcur[b], lhist[b]);
        __syncthreads();

        for (int i = threadIdx.x; i < cnt; i += 256) {
            int2 en = ent[i];
            int b = en.x >> 12;
            int off = atomicAdd(&lcur[b], 1);
            int idx = gposl[b] + off;
            if (idx < SBCAP) btmp[(size_t)b * SBCAP + idx] = en;
        }
    } else if (bid < NBLK_A1 + XH_BLOCKS) {
        // ---- role: xh (x fp32 -> fp16) ----
        for (int i = (bid - NBLK_A1) * 256 + threadIdx.x; i < XH_TOTAL;
             i += XH_BLOCKS * 256) {
            float4 v = ((const float4*)x)[i];
            f16x4 o = {(f16)v.x, (f16)v.y, (f16)v.z, (f16)v.w};
            *(f16x4*)(xh + (size_t)i * 4) = o;
        }
    } else {
        // ---- role: wbuild (Wb_t[512][128] permuted + W2_t[16][64]) ----
        const int t0 = (bid - NBLK_A1 - XH_BLOCKS) * 256 + threadIdx.x;
        for (int idx = t0; idx < 512 * 128; idx += WB_BLOCKS * 256) {
            int p = idx >> 7, k = idx & 127;
            int lp = p & 63;
            int lc = ((lp & 15) >> 2) * 16 + ((lp >> 4) << 2) + (lp & 3);
            int col = (p & ~63) | lc;               // logical output column
            float v;
            if (col < 64) {
                v = root1[k * HID_CH + col];
            } else {
                int cc = col - 64, r = cc >> 6, inner = cc & 63, b = inner >> 4, j = inner & 15;
                int kb = k - b * 32;
                v = (kb >= 0 && kb < 32) ? W1[(((r * 4 + b) * 32) + kb) * 16 + j] : 0.f;
            }
            wbt[idx] = (f16)v;
        }
        for (int idx = t0; idx < 16 * 64; idx += WB_BLOCKS * 256) {
            int col = idx >> 6, k = idx & 63;
            float v;
            if (col < 14) {
                int r = col >> 1, oc = col & 1;
                v = 0.f;
                for (int b = 0; b < 4; ++b) v += comp2[r * 4 + b] * basis2[(b * 64 + k) * 2 + oc];
            } else {
                v = root2[k * 2 + (col - 14)];
            }
            w2t[idx] = (f16)v;
        }
    }
}

// ========== gemm1 (MFMA, LDS-free, barrier-free) with 2-DEEP register prefetch ==========
// Latency model: per tile, ~150 cyc MFMA+store work vs ~400-900 cyc A-load latency (xh
// is L3-resident, 25.6MB > L2) with only ~2.4 waves/SIMD -> single-depth prefetch leaves
// the wave stalled most of each iteration. Two named buffers (aA/aB, static indexing):
// loads for tile t+2 are issued during t's epilogue -> 2 iterations of work cover the
// latency. launch_bounds(512,4) holds the <=128-total-VGPR occupancy band.
__global__ __launch_bounds__(512, 4)
void gemm1_kernel(const f16* __restrict__ xh, const f16* __restrict__ wbt,
                  f16* __restrict__ dense1) {
    const int lane = threadIdx.x & 63;
    const int wv = threadIdx.x >> 6;
    const int m = lane & 15;
    const int quad = lane >> 4;
    const int G = gridDim.x;

    f16x8 bf[4][4];
#pragma unroll
    for (int t = 0; t < 4; ++t) {
        const f16* wc = wbt + (size_t)(wv * 64 + t * 16 + m) * 128 + quad * 8;
#pragma unroll
        for (int kk = 0; kk < 4; ++kk)
            bf[t][kk] = *(const f16x8*)(wc + kk * 32);
    }

    const f16* xbase = xh + (size_t)m * 128 + quad * 8;   // + tile*16*128 per tile

    int tile = blockIdx.x;
    f16x8 aA[4], aB[4];
    if (tile < NTILES) {
        const f16* xr = xbase + (size_t)tile * 2048;
#pragma unroll
        for (int kk = 0; kk < 4; ++kk) aA[kk] = *(const f16x8*)(xr + kk * 32);
    }
    if (tile + G < NTILES) {
        const f16* xr = xbase + (size_t)(tile + G) * 2048;
#pragma unroll
        for (int kk = 0; kk < 4; ++kk) aB[kk] = *(const f16x8*)(xr + kk * 32);
    }

    while (tile < NTILES) {
        // ---- phase A: compute tile (aA), prefetch tile+2G into aA ----
        {
            f16x8 hv[2];
#pragma unroll
            for (int t = 0; t < 4; ++t) {
                f32x4 acc = {0.f, 0.f, 0.f, 0.f};
#pragma unroll
                for (int kk = 0; kk < 4; ++kk)
                    acc = __builtin_amdgcn_mfma_f32_16x16x32_f16(bf[t][kk], aA[kk], acc, 0, 0, 0);
#pragma unroll
                for (int i = 0; i < 4; ++i)
                    hv[t >> 1][(t & 1) * 4 + i] = (f16)acc[i];
            }
            if (tile + 2 * G < NTILES) {
                const f16* xr = xbase + (size_t)(tile + 2 * G) * 2048;
#pragma unroll
                for (int kk = 0; kk < 4; ++kk) aA[kk] = *(const f16x8*)(xr + kk * 32);
            }
            f16* dst = dense1 + (size_t)(tile * 16 + m) * 512 + wv * 64 + quad * 16;
            *(f16x8*)dst       = hv[0];
            *(f16x8*)(dst + 8) = hv[1];
        }
        tile += G;
        if (tile >= NTILES) break;

        // ---- phase B: compute tile (aB), prefetch tile+2G into aB ----
        {
            f16x8 hv[2];
#pragma unroll
            for (int t = 0; t < 4; ++t) {
                f32x4 acc = {0.f, 0.f, 0.f, 0.f};
#pragma unroll
                for (int kk = 0; kk < 4; ++kk)
                    acc = __builtin_amdgcn_mfma_f32_16x16x32_f16(bf[t][kk], aB[kk], acc, 0, 0, 0);
#pragma unroll
                for (int i = 0; i < 4; ++i)
                    hv[t >> 1][(t & 1) * 4 + i] = (f16)acc[i];
            }
            if (tile + 2 * G < NTILES) {
                const f16* xr = xbase + (size_t)(tile + 2 * G) * 2048;
#pragma unroll
                for (int kk = 0; kk < 4; ++kk) aB[kk] = *(const f16x8*)(xr + kk * 32);
            }
            f16* dst = dense1 + (size_t)(tile * 16 + m) * 512 + wv * 64 + quad * 16;
            *(f16x8*)dst       = hv[0];
            *(f16x8*)(dst + 8) = hv[1];
        }
        tile += G;
    }
}

// ========== passA2: 256 thr, bucketscan INLINED (round-3 proven) ==========
__global__ __launch_bounds__(256)
void passA2_kernel(const int* __restrict__ gcur, const int2* __restrict__ btmp,
                   int* __restrict__ off2, int* __restrict__ packed1) {
    __shared__ int hist[4096];  // 16 KB: bucket-local bins (d&511)*8+r
    __shared__ int aux[256];
    __shared__ int shv[1];
    const int b = blockIdx.x >> 2;
    const int q = blockIdx.x & 3;
    const int t = threadIdx.x;

    if (blockIdx.x == 0 && t == 0) off2[0] = 0;

    // phase 0: inline bucket-base scan over gcur[0..NSB)
    int v0 = (t < NSB) ? min(gcur[t], SBCAP) : 0;
    aux[t] = v0;
    __syncthreads();
    for (int d = 1; d < 256; d <<= 1) {
        int xv = (t >= d) ? aux[t - d] : 0;
        __syncthreads();
        if (t >= d) aux[t] += xv;
        __syncthreads();
    }
    if (t == 0) shv[0] = (b == 0) ? 0 : aux[b - 1];   // exclusive base
    __syncthreads();
    const int gb = shv[0];
    const int cnt = min(gcur[b], SBCAP);
    const int2* base = btmp + (size_t)b * SBCAP;
    __syncthreads();                                  // aux reused below

    // phase 1: bucket-local histogram
    for (int i = t; i < 4096; i += 256) hist[i] = 0;
    __syncthreads();
    for (int i = t; i < cnt; i += 256) atomicAdd(&hist[base[i].x & 4095], 1);
    __syncthreads();

    // phase 2: block-wide exclusive scan over 4096 bins (16 bins/thread)
    int loc[16];
    int run = 0;
#pragma unroll
    for (int j = 0; j < 16; ++j) { loc[j] = run; run += hist[t * 16 + j]; }
    aux[t] = run;
    __syncthreads();
    for (int d = 1; d < 256; d <<= 1) {
        int xv = (t >= d) ? aux[t - d] : 0;
        __syncthreads();
        if (t >= d) aux[t] += xv;
        __syncthreads();
    }
    const int tbase = aux[t] - run;
    __syncthreads();

#pragma unroll
    for (int j = 0; j < 16; ++j) {
        int bin = t * 16 + j;
        int excl = tbase + loc[j];
        int incl = excl + hist[bin];            // read before overwrite (same bin)
        if ((t >> 6) == q) {                    // my quarter's bins only
            int gkey = (b << 12) + bin;
            if (gkey < NBINS) off2[gkey + 1] = gb + incl;
        }
        hist[bin] = excl;                       // becomes bucket-relative cursor
    }
    __syncthreads();

    for (int i = t; i < cnt; i += 256) {        // place my quarter's edges
        int2 e = base[i];
        int lb = e.x & 4095;
        if ((lb >> 10) == q) {
            int pos = gb + atomicAdd(&hist[lb], 1);
            packed1[pos] = e.y;
        }
    }
}

// ========== agg1+pre2 FUSED (round-6 proven form: single node/wave, unroll 8) ==========
__global__ __launch_bounds__(256)
void agg1_kernel(const f16* __restrict__ dense1, const float* __restrict__ bias1,
                 const float* __restrict__ bias2, const f16* __restrict__ w2t,
                 const int* __restrict__ off2, const int* __restrict__ packed1,
                 float* __restrict__ msg2)
{
    __shared__ float hbuf[4][64];
    const int lane = threadIdx.x & 63;
    const int lane2 = lane * 2;
    const int wv = threadIdx.x >> 6;
    const char* m1 = (const char*)dense1;
    const int wid = blockIdx.x * 4 + wv;
    const int nw = gridDim.x * 4;
    const float bias = bias1[lane];

    // per-lane W2 slice: lane (kq, c) holds w2t[c][kq*16 .. +16) as f32
    const int c = lane & 15;
    const int kq = lane >> 4;
    float w2v[16];
#pragma unroll
    for (int j = 0; j < 16; ++j) w2v[j] = (float)w2t[c * 64 + kq * 16 + j];
    const float badd = (c == 14) ? bias2[0] : ((c == 15) ? bias2[1] : 0.f);

    for (int n = wid; n < N_NODES; n += nw) {
        const int st = off2[n << 3];
        const int en = off2[(n << 3) + 7];
        const float hroot = (float)dense1[(size_t)n * 512 + lane];  // issue early
        float add = 0.f, cur = 0.f;
        int prev_r = -1;

#define MRG(kk, vv) { \
        int r_ = (int)((kk) >> 28); \
        bool same_ = (r_ == prev_r); \
        add += same_ ? 0.f : cur; \
        cur = same_ ? fmaxf(cur, (vv)) : (vv); \
        prev_r = r_; }

        int p = st;
        for (; p + 7 < en; p += 8) {
            unsigned k0 = (unsigned)packed1[p];
            unsigned k1 = (unsigned)packed1[p + 1];
            unsigned k2 = (unsigned)packed1[p + 2];
            unsigned k3 = (unsigned)packed1[p + 3];
            unsigned k4 = (unsigned)packed1[p + 4];
            unsigned k5 = (unsigned)packed1[p + 5];
            unsigned k6 = (unsigned)packed1[p + 6];
            unsigned k7 = (unsigned)packed1[p + 7];
            float v0 = (float)*(const f16*)(m1 + (k0 & OFFM) + lane2);
            float v1 = (float)*(const f16*)(m1 + (k1 & OFFM) + lane2);
            float v2 = (float)*(const f16*)(m1 + (k2 & OFFM) + lane2);
            float v3 = (float)*(const f16*)(m1 + (k3 & OFFM) + lane2);
            float v4 = (float)*(const f16*)(m1 + (k4 & OFFM) + lane2);
            float v5 = (float)*(const f16*)(m1 + (k5 & OFFM) + lane2);
            float v6 = (float)*(const f16*)(m1 + (k6 & OFFM) + lane2);
            float v7 = (float)*(const f16*)(m1 + (k7 & OFFM) + lane2);
            MRG(k0, v0) MRG(k1, v1) MRG(k2, v2) MRG(k3, v3)
            MRG(k4, v4) MRG(k5, v5) MRG(k6, v6) MRG(k7, v7)
        }
        for (; p + 3 < en; p += 4) {
            unsigned k0 = (unsigned)packed1[p];
            unsigned k1 = (unsigned)packed1[p + 1];
            unsigned k2 = (unsigned)packed1[p + 2];
            unsigned k3 = (unsigned)packed1[p + 3];
            float v0 = (float)*(const f16*)(m1 + (k0 & OFFM) + lane2);
            float v1 = (float)*(const f16*)(m1 + (k1 & OFFM) + lane2);
            float v2 = (float)*(const f16*)(m1 + (k2 & OFFM) + lane2);
            float v3 = (float)*(const f16*)(m1 + (k3 & OFFM) + lane2);
            MRG(k0, v0) MRG(k1, v1) MRG(k2, v2) MRG(k3, v3)
        }
        for (; p < en; ++p) {
            unsigned k0 = (unsigned)packed1[p];
            float v0 = (float)*(const f16*)(m1 + (k0 & OFFM) + lane2);
            MRG(k0, v0)
        }
#undef MRG
        add += cur;

        const float hval = fmaxf(hroot + bias + add, 0.f);  // final layer-1 h (f32)

        // ---- fused pre2: msg2[n][c] = sum_k h[k] * W2[k][c] (+bias2 on 14/15) ----
        hbuf[wv][lane] = hval;               // intra-wave LDS broadcast (in-order DS)
        float part = 0.f;
#pragma unroll
        for (int j = 0; j < 16; ++j) part += hbuf[wv][kq * 16 + j] * w2v[j];
        part += __shfl_xor(part, 16);
        part += __shfl_xor(part, 32);
        if (lane < 16) msg2[(size_t)n * 16 + c] = part + badd;
    }
}

// ========== agg2: thread/node; merged edge loop, unroll 8 (unchanged) ==========
__global__ __launch_bounds__(256)
void agg2_kernel(const float* __restrict__ msg2, const int* __restrict__ off2,
                 const int* __restrict__ packed1, float* __restrict__ out)
{
    const int n = blockIdx.x * blockDim.x + threadIdx.x;
    if (n >= N_NODES) return;
    const char* m2 = (const char*)msg2;
    const int st = off2[n << 3];
    const int en = off2[(n << 3) + 7];
    float addx = 0.f, addy = 0.f, curx = 0.f, cury = 0.f;
    int prev_r = -1;

#define MRG2(kk, ff) { \
    int r_ = (int)((kk) >> 28); \
    bool same_ = (r_ == prev_r); \
    addx += same_ ? 0.f : curx; \
    addy += same_ ? 0.f : cury; \
    curx = same_ ? fmaxf(curx, (ff).x) : (ff).x; \
    cury = same_ ? fmaxf(cury, (ff).y) : (ff).y; \
    prev_r = r_; }

    int p = st;
    for (; p + 7 < en; p += 8) {
        unsigned k0 = (unsigned)packed1[p],     k1 = (unsigned)packed1[p + 1];
        unsigned k2 = (unsigned)packed1[p + 2], k3 = (unsigned)packed1[p + 3];
        unsigned k4 = (unsigned)packed1[p + 4], k5 = (unsigned)packed1[p + 5];
        unsigned k6 = (unsigned)packed1[p + 6], k7 = (unsigned)packed1[p + 7];
        float2 f0 = *(const float2*)(m2 + (((k0 & OFFM) >> 4) - 8));
        float2 f1 = *(const float2*)(m2 + (((k1 & OFFM) >> 4) - 8));
        float2 f2 = *(const float2*)(m2 + (((k2 & OFFM) >> 4) - 8));
        float2 f3 = *(const float2*)(m2 + (((k3 & OFFM) >> 4) - 8));
        float2 f4 = *(const float2*)(m2 + (((k4 & OFFM) >> 4) - 8));
        float2 f5 = *(const float2*)(m2 + (((k5 & OFFM) >> 4) - 8));
        float2 f6 = *(const float2*)(m2 + (((k6 & OFFM) >> 4) - 8));
        float2 f7 = *(const float2*)(m2 + (((k7 & OFFM) >> 4) - 8));
        MRG2(k0, f0) MRG2(k1, f1) MRG2(k2, f2) MRG2(k3, f3)
        MRG2(k4, f4) MRG2(k5, f5) MRG2(k6, f6) MRG2(k7, f7)
    }
    for (; p < en; ++p) {
        unsigned k0 = (unsigned)packed1[p];
        float2 f0 = *(const float2*)(m2 + (((k0 & OFFM) >> 4) - 8));
        MRG2(k0, f0)
    }
#undef MRG2

    out[(size_t)n * 2 + 0] = msg2[(size_t)n * 16 + 14] + addx + curx;
    out[(size_t)n * 2 + 1] = msg2[(size_t)n * 16 + 15] + addy + cury;
}

extern "C" void kernel_launch(void* const* d_in, const int* in_sizes, int n_in,
                              void* d_out, int out_size, void* d_ws, size_t ws_size,
                              hipStream_t stream)
{
    const float* x      = (const float*)d_in[0];
    const int*   ei     = (const int*)d_in[1];
    const int*   et     = (const int*)d_in[2];
    const float* W1     = (const float*)d_in[3];
    const float* root1  = (const float*)d_in[4];
    const float* bias1  = (const float*)d_in[5];
    const float* comp2  = (const float*)d_in[6];
    const float* basis2 = (const float*)d_in[7];
    const float* root2  = (const float*)d_in[8];
    const float* bias2  = (const float*)d_in[9];
    float* out = (float*)d_out;

    // workspace carve-up
    char* ws = (char*)d_ws;
    size_t o = 0;
    auto carve = [&](size_t bytes) { char* p = ws + o; o += (bytes + 255) & ~(size_t)255; return p; };
    int*   off2    = (int*)carve(sizeof(int) * (NBINS + 1));
    int*   gcur    = (int*)carve(sizeof(int) * NSB);
    int2*  btmp    = (int2*)carve(sizeof(int2) * (size_t)NSB * SBCAP);           // 12.8 MB
    int*   packed1 = (int*)carve(sizeof(int) * N_EDGESV);
    f16*   xh      = (f16*)carve(sizeof(f16) * (size_t)N_NODES * IN_CH);         // 25.6 MB
    f16*   wbt     = (f16*)carve(sizeof(f16) * 512 * 128);
    f16*   w2t     = (f16*)carve(sizeof(f16) * 16 * 64);
    f16*   dense1  = (f16*)carve(sizeof(f16) * (size_t)N_NODES * 512);           // 102.4 MB
    float* msg2    = (float*)carve(sizeof(float) * (size_t)N_NODES * 16);        //  6.4 MB

    hipMemsetAsync(gcur, 0, sizeof(int) * NSB, stream);

    // K1: passA1 | xh | wbuild (independent roles)
    k1_fused_kernel<<<NBLK_A1 + XH_BLOCKS + WB_BLOCKS, 256, 0, stream>>>(
        ei, et, gcur, btmp, x, xh, root1, W1, comp2, basis2, root2, wbt, w2t);

    // dense precompute (2-deep prefetch pipeline)
    gemm1_kernel<<<1024, 512, 0, stream>>>(xh, wbt, dense1);

    // CSR finalize (bucketscan inlined)
    passA2_kernel<<<NSB * 4, 256, 0, stream>>>(gcur, btmp, off2, packed1);

    // layer-1 aggregation + fused layer-2 message precompute (round-6 proven)
    agg1_kernel<<<2048, 256, 0, stream>>>(dense1, bias1, bias2, w2t, off2, packed1, msg2);

    // layer-2 aggregation
    agg2_kernel<<<(N_NODES + 255) / 256, 256, 0, stream>>>(msg2, off2, packed1, out);
}